// Round 8
// baseline (111.948 us; speedup 1.0000x reference)
//
#include <hip/hip_runtime.h>
#include <hip/hip_bf16.h>
#include <math.h>

// SupCon loss, N=8192 D=128 fp32 in, scalar fp32 out.
// Round 8: ONE barrier total. Stage the whole 256-col x K=128 B-chunk (64 KB)
// into LDS up front, __syncthreads once, then 8 waves free-run through the
// 4 col-tiles with no further sync -- pipes (LDS/MFMA/VALU) overlap across
// 16 waves/CU instead of phase-locking at per-tile barriers (R7 lesson).
// A-fragments live in registers (loaded once from global, L2-resident).
// Partials layout pE[chunk*N + row]: block-private contiguous lines (R7's
// row-major layout caused 16-way cross-XCD partial-line write amplification).
// R6 lesson: never read MFMA B-frags straight from global (16-line scatter).
// R4 lesson: no column atomics. Fb = f/||f|| * sqrt(10*log2e) -> acc is
// log2-domain: exp(sim) = exp2(acc).

constexpr int N = 8192;
constexpr int D = 128;

typedef __attribute__((ext_vector_type(8))) short short8;  // 8 bf16 = 4 VGPRs
typedef __attribute__((ext_vector_type(4))) float f32x4;

__device__ __forceinline__ float fast_exp2(float x) {
#if __has_builtin(__builtin_amdgcn_exp2f)
    return __builtin_amdgcn_exp2f(x);
#else
    return __expf(x * 0.69314718056f);
#endif
}

__device__ __forceinline__ void gload_lds16(const void* g, void* s) {
    __builtin_amdgcn_global_load_lds(
        (const __attribute__((address_space(1))) unsigned int*)g,
        (__attribute__((address_space(3))) unsigned int*)s, 16, 0, 0);
}

// ---------------- prep: bf16 rows scaled into log2 domain -------------------
__global__ void prep_kernel(const float* __restrict__ F,
                            unsigned short* __restrict__ Fb) {
    int row = blockIdx.x * 16 + (threadIdx.x >> 6);  // 512 blocks x 16 rows
    int l = threadIdx.x & 63;
    float2 v = ((const float2*)(F + (size_t)row * D))[l];
    float ss = v.x * v.x + v.y * v.y;
#pragma unroll
    for (int off = 32; off > 0; off >>= 1) ss += __shfl_xor(ss, off);
    float sc = sqrtf(14.4269504089f / ss);  // 10 * log2(e), folded
    __hip_bfloat16 hx = __float2bfloat16(v.x * sc);
    __hip_bfloat16 hy = __float2bfloat16(v.y * sc);
    ushort2 u;
    u.x = *(unsigned short*)&hx;
    u.y = *(unsigned short*)&hy;
    ((ushort2*)(Fb + (size_t)row * D))[l] = u;
}

// Stage a 256-row x 128-k bf16 chunk (64 KB) with 8 waves x 8 iters x 1 KB.
// LDS dest is wave-uniform base + lane*16 (m104/m108): lane-contiguous.
// Source-side XOR swizzle so compute-side ds_read_b128 spreads banks.
__device__ __forceinline__ void stage_chunk(const unsigned short* __restrict__ src,
                                            unsigned short* dst, int w, int l) {
    int lr = l >> 4, lq = l & 15;
#pragma unroll
    for (int it = 0; it < 8; ++it) {
        int a = w * 8 + it;        // 1 KB group 0..63
        int r = a * 4 + lr;        // chunk row 0..255
        int q = lq ^ (r & 7);      // swizzled source 16B-block
        gload_lds16(src + (size_t)r * D + q * 8, dst + a * 512);
    }
}

// ---------------- sim: 256 rows x 256-col chunk, single barrier -------------
// Grid (32 chunks, 32 row-blocks) x 512 thr = 1024 blocks = exactly 2/CU.
// Wave w owns rows [i0 + w*32, +32): af[2][4] in regs; B chunk shared in LDS.
__global__ __launch_bounds__(512, 4) void sim_kernel(
    const unsigned short* __restrict__ Fb, const int* __restrict__ labels,
    float* __restrict__ pE, float* __restrict__ pP) {
    __shared__ unsigned short Bt[256 * D];  // 64 KB: 4 col-tiles of 64

    const int chunk = blockIdx.x;   // 0..31 (256-col chunk)
    const int rb = blockIdx.y;      // 0..31 (256-row block)
    const int i0 = rb * 256, j0 = chunk * 256;
    const int t = threadIdx.x, w = t >> 6, l = t & 63;
    const int c = l & 15, quad = l >> 4;

    stage_chunk(Fb + (size_t)j0 * D, Bt, w, l);

    // A fragments: persistent, 2 row-bands x 4 k-steps = 32 VGPRs
    short8 af[2][4];
    int li[2][4];
#pragma unroll
    for (int mb = 0; mb < 2; ++mb) {
        const unsigned short* ar = Fb + (size_t)(i0 + w * 32 + mb * 16 + c) * D;
#pragma unroll
        for (int kk = 0; kk < 4; ++kk)
            af[mb][kk] = *(const short8*)(ar + (kk * 4 + quad) * 8);
#pragma unroll
        for (int r = 0; r < 4; ++r)
            li[mb][r] = labels[i0 + w * 32 + mb * 16 + quad * 4 + r];
    }

    __syncthreads();  // the ONLY barrier: DMA drained, chunk resident

    float RE[2][4] = {}, RP[2][4] = {};
    const bool diagBlk = (chunk == rb);

#pragma unroll 1
    for (int s = 0; s < 4; ++s) {  // 4 col-tiles of 64, no sync between
        const int jb = s * 64;     // tile base row in Bt
        int lj[4];
#pragma unroll
        for (int n = 0; n < 4; ++n) lj[n] = labels[j0 + jb + n * 16 + c];

        f32x4 acc[2][4] = {};
#pragma unroll
        for (int kk = 0; kk < 4; ++kk) {
            int sl = (kk * 4 + quad) ^ (c & 7);  // undo swizzle (row&7 == c&7)
            short8 bf[4];
#pragma unroll
            for (int n = 0; n < 4; ++n)
                bf[n] = *(const short8*)&Bt[(jb + n * 16 + c) * D + sl * 8];
#pragma unroll
            for (int mb = 0; mb < 2; ++mb)
#pragma unroll
                for (int n = 0; n < 4; ++n)
                    acc[mb][n] = __builtin_amdgcn_mfma_f32_16x16x32_bf16(
                        af[mb][kk], bf[n], acc[mb][n], 0, 0, 0);
        }

        // epilogue: C/D row = quad*4+r (+band), col = c (+n*16)
        if (diagBlk && s == (w >> 1)) {  // wave-uniform diagonal branch
#pragma unroll
            for (int mb = 0; mb < 2; ++mb)
#pragma unroll
                for (int n = 0; n < 4; ++n)
#pragma unroll
                    for (int r = 0; r < 4; ++r) {
                        float s2 = acc[mb][n][r];
                        bool self = ((w & 1) * 32 + mb * 16 + quad * 4 + r) ==
                                    (n * 16 + c);
                        bool pos = (li[mb][r] == lj[n]) && !self;
                        RE[mb][r] += self ? 0.0f : fast_exp2(s2);
                        RP[mb][r] += pos ? s2 : 0.0f;
                    }
        } else {
#pragma unroll
            for (int mb = 0; mb < 2; ++mb)
#pragma unroll
                for (int n = 0; n < 4; ++n)
#pragma unroll
                    for (int r = 0; r < 4; ++r) {
                        float s2 = acc[mb][n][r];
                        RE[mb][r] += fast_exp2(s2);
                        RP[mb][r] += (li[mb][r] == lj[n]) ? s2 : 0.0f;
                    }
        }
    }

    // reduce across the 16 c-lanes; block-private contiguous stores (no RMW)
#pragma unroll
    for (int mb = 0; mb < 2; ++mb)
#pragma unroll
        for (int r = 0; r < 4; ++r) {
#pragma unroll
            for (int off = 1; off < 16; off <<= 1) {
                RE[mb][r] += __shfl_xor(RE[mb][r], off);
                RP[mb][r] += __shfl_xor(RP[mb][r], off);
            }
        }
    if (c == 0) {
#pragma unroll
        for (int mb = 0; mb < 2; ++mb)
#pragma unroll
            for (int r = 0; r < 4; ++r) {
                int row = i0 + w * 32 + mb * 16 + quad * 4 + r;
                pE[(size_t)chunk * N + row] = RE[mb][r];
                pP[(size_t)chunk * N + row] = RP[mb][r];
            }
    }
}

// ---------------- finalize: single block, hist once, coalesced partials -----
__global__ void finalize_kernel(const float* __restrict__ pE,
                                const float* __restrict__ pP,
                                const int* __restrict__ labels,
                                float* __restrict__ out) {
    __shared__ int h[1024];
    __shared__ float ws16[16];
    int t = threadIdx.x;  // 1024 threads
    h[t] = 0;
    __syncthreads();
    for (int i = t; i < N; i += 1024) atomicAdd(&h[labels[i]], 1);
    __syncthreads();

    float a = 0.0f;
#pragma unroll 1
    for (int k = 0; k < 8; ++k) {
        int row = t + k * 1024;  // coalesced across lanes for every chunk read
        int cnt = h[labels[row]] - 1;
        float E = 0.0f, P = 0.0f;
#pragma unroll
        for (int ch = 0; ch < 32; ++ch) {
            E += pE[(size_t)ch * N + row];
            P += pP[(size_t)ch * N + row];
        }
        if (cnt > 0)
            a += __logf(E + 1e-9f) - 0.69314718056f * P / (float)cnt;
    }
#pragma unroll
    for (int off = 32; off > 0; off >>= 1) a += __shfl_xor(a, off);
    if ((t & 63) == 0) ws16[t >> 6] = a;
    __syncthreads();
    if (t == 0) {
        float s = 0.0f;
#pragma unroll
        for (int i = 0; i < 16; ++i) s += ws16[i];
        out[0] = s / (float)N;
    }
}

extern "C" void kernel_launch(void* const* d_in, const int* in_sizes, int n_in,
                              void* d_out, int out_size, void* d_ws, size_t ws_size,
                              hipStream_t stream) {
    const float* F      = (const float*)d_in[0];
    const int*   labels = (const int*)d_in[1];
    float* out = (float*)d_out;

    unsigned short* Fb = (unsigned short*)d_ws;   // N*D bf16 = 2 MB
    float* pE = (float*)(Fb + (size_t)N * D);     // 32*N floats = 1 MB
    float* pP = pE + (size_t)32 * N;              // 32*N floats = 1 MB

    prep_kernel<<<N / 16, 1024, 0, stream>>>(F, Fb);
    sim_kernel<<<dim3(32, 32), 512, 0, stream>>>(Fb, labels, pE, pP);
    finalize_kernel<<<1, 1024, 0, stream>>>(pE, pP, labels, out);
}